// Round 6
// baseline (69.222 us; speedup 1.0000x reference)
//
#include <hip/hip_runtime.h>

#define LAMB_COORD 5.0f
#define LAMB_NOOBJ 0.5f
#define GEPS 1e-7f

// gt/pred: (B=16384, C=30, H=7, W=7) fp32. Record = 1470 floats.
// ONE WAVE PER RECORD, fully wave-autonomous (no __syncthreads in the hot path):
//   1) issue class-region float2 stream loads (ch 10..29, 980 floats, 8B-aligned)
//   2) lanes 0..48: 20 stride-49 front loads + GIoU/argmax/front loss, appears in reg
//   3) consume class stream; mask via __shfl(appears, hw), hw tracked incrementally
//      (490 % 49 == 0 -> hw = 2*idx mod 49, step +30 mod 49 per 64-lane round)
//   4) single end-of-block reduce (wave shuffle -> LDS -> 1 atomic per block).

__global__ __launch_bounds__(256) void yolo_loss_kernel(
        const float* __restrict__ gt, const float* __restrict__ pred,
        float* __restrict__ out) {
    const int tid  = threadIdx.x;
    const int lane = tid & 63;
    const int wid  = tid >> 6;
    const int rec  = blockIdx.x * 4 + wid;           // 4096 blocks x 4 waves
    const float* __restrict__ g = gt   + (size_t)rec * 1470;
    const float* __restrict__ p = pred + (size_t)rec * 1470;

    // ---- 1) Class stream: issue ALL 32 float2 loads up front ----
    const float2* __restrict__ gc = (const float2*)(g + 490);  // 490 float2
    const float2* __restrict__ pc = (const float2*)(p + 490);
    float2 vg[8], vp[8];
    #pragma unroll
    for (int k = 0; k < 8; ++k) {
        int idx = lane + 64 * k;
        int ii = (idx < 490) ? idx : 0;   // safe dup for tail, stays unconditional
        vg[k] = gc[ii];
        vp[k] = pc[ii];
    }
    __builtin_amdgcn_sched_barrier(0);   // pin class loads above the front phase

    // ---- 2) Front: lane == cell (0..48) ----
    float s = 0.0f;
    float appears = 0.0f;
    if (lane < 49) {
        float gv[10], pv[10];
        #pragma unroll
        for (int c = 0; c < 10; ++c) { gv[c] = g[c * 49 + lane]; pv[c] = p[c * 49 + lane]; }

        const float gx1 = gv[0], gy1 = gv[1];
        const float gx2 = gv[0] + gv[2], gy2 = gv[1] + gv[3];
        const float ga  = (gx2 - gx1) * (gy2 - gy1);

        float l[2];
        #pragma unroll
        for (int k = 0; k < 2; ++k) {
            const int o = k * 5;
            float px1 = pv[o + 0], py1 = pv[o + 1];
            float px2 = px1 + pv[o + 2], py2 = py1 + pv[o + 3];
            float ix1 = fmaxf(gx1, px1), iy1 = fmaxf(gy1, py1);
            float ix2 = fminf(gx2, px2), iy2 = fminf(gy2, py2);
            float inter = fmaxf(ix2 - ix1, 0.0f) * fmaxf(iy2 - iy1, 0.0f);
            float pa  = (px2 - px1) * (py2 - py1);
            float uni = ga + pa - inter;
            float iou = inter / (uni + GEPS);
            float cx1 = fminf(gx1, px1), cy1 = fminf(gy1, py1);
            float cx2 = fmaxf(gx2, px2), cy2 = fmaxf(gy2, py2);
            float enc = (cx2 - cx1) * (cy2 - cy1);
            l[k] = 1.0f - (iou - (enc - uni) / (enc + GEPS));
        }

        // jnp.argmax first-max tie-break: arg = 1 iff l2 > l1
        float r0, r1;
        if (l[1] > l[0]) { r0 = 0.0f;   r1 = gv[9]; }
        else             { r0 = gv[4];  r1 = 0.0f;  }
        appears = fmaxf(r0, r1);

        float d;
        d = gv[0] - pv[0]; s += d * d * r0 * LAMB_COORD;
        d = gv[1] - pv[1]; s += d * d * r0 * LAMB_COORD;
        d = gv[5] - pv[5]; s += d * d * r1 * LAMB_COORD;
        d = gv[6] - pv[6]; s += d * d * r1 * LAMB_COORD;
        d = sqrtf(gv[2]) - sqrtf(pv[2]); s += d * d * r0 * LAMB_COORD;
        d = sqrtf(gv[3]) - sqrtf(pv[3]); s += d * d * r0 * LAMB_COORD;
        d = sqrtf(gv[7]) - sqrtf(pv[7]); s += d * d * r1 * LAMB_COORD;
        d = sqrtf(gv[8]) - sqrtf(pv[8]); s += d * d * r1 * LAMB_COORD;
        d = gv[4] - pv[4]; { float d2 = d * d; s += d2 * r0 + d2 * (1.0f - r0) * LAMB_NOOBJ; }
        d = gv[9] - pv[9]; { float d2 = d * d; s += d2 * r1 + d2 * (1.0f - r1) * LAMB_NOOBJ; }
    }

    // ---- 3) Consume class stream with shuffled appears mask ----
    // element e = 490 + 2*(lane + 64k); hw = e mod 49 = (2*lane + 30k) mod 49
    int hw = 2 * lane;
    if (hw >= 98) hw -= 98; else if (hw >= 49) hw -= 49;
    #pragma unroll
    for (int k = 0; k < 8; ++k) {
        int idx = lane + 64 * k;
        if (idx < 490) {
            int hw1 = hw + 1; if (hw1 == 49) hw1 = 0;
            float a0 = __shfl(appears, hw, 64);
            float a1 = __shfl(appears, hw1, 64);
            float d0 = vg[k].x - vp[k].x;
            float d1 = vg[k].y - vp[k].y;
            s = fmaf(a0 * d0, d0, s);
            s = fmaf(a1 * d1, d1, s);
        }
        hw += 30; if (hw >= 49) hw -= 49;
    }

    // ---- 4) Reduce: wave shuffle -> LDS -> one atomic per block ----
    #pragma unroll
    for (int off = 32; off > 0; off >>= 1)
        s += __shfl_down(s, off, 64);

    __shared__ float wsum[4];
    if (lane == 0) wsum[wid] = s;
    __syncthreads();
    if (tid == 0) {
        atomicAdd(out, wsum[0] + wsum[1] + wsum[2] + wsum[3]);
    }
}

extern "C" void kernel_launch(void* const* d_in, const int* in_sizes, int n_in,
                              void* d_out, int out_size, void* d_ws, size_t ws_size,
                              hipStream_t stream) {
    const float* gt   = (const float*)d_in[0];
    const float* pred = (const float*)d_in[1];
    float* out = (float*)d_out;

    const int B = in_sizes[0] / 1470;    // 16384 records
    const int grid = B / 4;              // 4096 blocks, 4 waves each

    hipMemsetAsync(out, 0, sizeof(float) * out_size, stream);
    yolo_loss_kernel<<<grid, 256, 0, stream>>>(gt, pred, out);
}

// Round 7
// 57.079 us; speedup vs baseline: 1.2127x; 1.2127x over previous
//
#include <hip/hip_runtime.h>

#define LAMB_COORD 5.0f
#define LAMB_NOOBJ 0.5f
#define GEPS 1e-7f

// gt/pred: (B=16384, C=30, H=7, W=7) fp32. Record = 1470 floats = 30ch x 49 cells.
// 2048 blocks x 256 threads; each block owns RPB=8 consecutive records.
// Phase A: loop over 392 cells; 20 stride-49 scalar loads (ch 0..9 of g,p) per
//          cell; GIoU/argmax/front loss (exact R1 formulas); appears -> LDS.
// Phase B: record-loop streaming the class region (980 floats/record) as
//          contiguous float2; per-element mask from LDS appears.
// Class float2 alignment: record stride 5880 B and class offset 1960 B are both
// divisible by 8.

#define RPB 8
#define CELLS (RPB * 49)          // 392
#define CLS2R 490                 // float2 per record class region

__global__ __launch_bounds__(256) void yolo_loss_kernel(
        const float* __restrict__ gt, const float* __restrict__ pred,
        float* __restrict__ out) {
    __shared__ float app[CELLS];

    const int tid = threadIdx.x;
    const size_t rec0 = (size_t)blockIdx.x * RPB;

    float s = 0.0f;

    // ---- Phase A: front (channels 0..9), one cell per thread-iteration ----
    for (int cell = tid; cell < CELLS; cell += 256) {
        const int rr = cell / 49;
        const int hw = cell - rr * 49;
        const float* __restrict__ g = gt   + (rec0 + rr) * 1470 + hw;
        const float* __restrict__ p = pred + (rec0 + rr) * 1470 + hw;

        float gv[10], pv[10];
        #pragma unroll
        for (int c = 0; c < 10; ++c) { gv[c] = g[c * 49]; pv[c] = p[c * 49]; }

        const float gx1 = gv[0], gy1 = gv[1];
        const float gx2 = gv[0] + gv[2], gy2 = gv[1] + gv[3];
        const float ga  = (gx2 - gx1) * (gy2 - gy1);

        float l[2];
        #pragma unroll
        for (int k = 0; k < 2; ++k) {
            const int o = k * 5;
            float px1 = pv[o + 0], py1 = pv[o + 1];
            float px2 = px1 + pv[o + 2], py2 = py1 + pv[o + 3];
            float ix1 = fmaxf(gx1, px1), iy1 = fmaxf(gy1, py1);
            float ix2 = fminf(gx2, px2), iy2 = fminf(gy2, py2);
            float inter = fmaxf(ix2 - ix1, 0.0f) * fmaxf(iy2 - iy1, 0.0f);
            float pa  = (px2 - px1) * (py2 - py1);
            float uni = ga + pa - inter;
            float iou = inter / (uni + GEPS);
            float cx1 = fminf(gx1, px1), cy1 = fminf(gy1, py1);
            float cx2 = fmaxf(gx2, px2), cy2 = fmaxf(gy2, py2);
            float enc = (cx2 - cx1) * (cy2 - cy1);
            l[k] = 1.0f - (iou - (enc - uni) / (enc + GEPS));
        }

        // jnp.argmax first-max tie-break: arg = 1 iff l2 > l1
        float r0, r1;
        if (l[1] > l[0]) { r0 = 0.0f;   r1 = gv[9]; }
        else             { r0 = gv[4];  r1 = 0.0f;  }
        app[cell] = fmaxf(r0, r1);

        float d;
        d = gv[0] - pv[0]; s += d * d * r0 * LAMB_COORD;
        d = gv[1] - pv[1]; s += d * d * r0 * LAMB_COORD;
        d = gv[5] - pv[5]; s += d * d * r1 * LAMB_COORD;
        d = gv[6] - pv[6]; s += d * d * r1 * LAMB_COORD;
        d = sqrtf(gv[2]) - sqrtf(pv[2]); s += d * d * r0 * LAMB_COORD;
        d = sqrtf(gv[3]) - sqrtf(pv[3]); s += d * d * r0 * LAMB_COORD;
        d = sqrtf(gv[7]) - sqrtf(pv[7]); s += d * d * r1 * LAMB_COORD;
        d = sqrtf(gv[8]) - sqrtf(pv[8]); s += d * d * r1 * LAMB_COORD;
        d = gv[4] - pv[4]; { float d2 = d * d; s += d2 * r0 + d2 * (1.0f - r0) * LAMB_NOOBJ; }
        d = gv[9] - pv[9]; { float d2 = d * d; s += d2 * r1 + d2 * (1.0f - r1) * LAMB_NOOBJ; }
    }
    __syncthreads();

    // ---- Phase B: class stream (channels 10..29) ----
    // q0 = tid, q1 = tid + 256 (< 490). hw(q) = (2q) mod 49, loop-invariant.
    const int q0 = tid;
    const int q1 = tid + 256;
    int h0 = (2 * q0) % 49;
    int h0n = (h0 == 48) ? 0 : h0 + 1;
    int h1 = (2 * q1) % 49;
    int h1n = (h1 == 48) ? 0 : h1 + 1;
    const bool do_q1 = (q1 < CLS2R);

    #pragma unroll 4
    for (int rr = 0; rr < RPB; ++rr) {
        const float2* __restrict__ gc = (const float2*)(gt   + (rec0 + rr) * 1470 + 490);
        const float2* __restrict__ pc = (const float2*)(pred + (rec0 + rr) * 1470 + 490);
        const int ab = rr * 49;

        float2 ga2 = gc[q0];
        float2 pa2 = pc[q0];
        float a0 = app[ab + h0];
        float a1 = app[ab + h0n];
        float d0 = ga2.x - pa2.x;
        float d1 = ga2.y - pa2.y;
        s += d0 * d0 * a0 + d1 * d1 * a1;

        if (do_q1) {
            float2 gb2 = gc[q1];
            float2 pb2 = pc[q1];
            float b0 = app[ab + h1];
            float b1 = app[ab + h1n];
            float e0 = gb2.x - pb2.x;
            float e1 = gb2.y - pb2.y;
            s += e0 * e0 * b0 + e1 * e1 * b1;
        }
    }

    // ---- Reduce: wave shuffle -> LDS -> one atomic per block ----
    #pragma unroll
    for (int off = 32; off > 0; off >>= 1)
        s += __shfl_down(s, off, 64);

    __shared__ float wsum[4];
    const int lane = tid & 63;
    const int wid  = tid >> 6;
    if (lane == 0) wsum[wid] = s;
    __syncthreads();
    if (tid == 0) {
        atomicAdd(out, wsum[0] + wsum[1] + wsum[2] + wsum[3]);
    }
}

extern "C" void kernel_launch(void* const* d_in, const int* in_sizes, int n_in,
                              void* d_out, int out_size, void* d_ws, size_t ws_size,
                              hipStream_t stream) {
    const float* gt   = (const float*)d_in[0];
    const float* pred = (const float*)d_in[1];
    float* out = (float*)d_out;

    const int B = in_sizes[0] / 1470;    // 16384
    const int grid = B / RPB;            // 2048

    hipMemsetAsync(out, 0, sizeof(float) * out_size, stream);
    yolo_loss_kernel<<<grid, 256, 0, stream>>>(gt, pred, out);
}